// Round 1
// baseline (109.867 us; speedup 1.0000x reference)
//
#include <hip/hip_runtime.h>
#include <hip/hip_bf16.h>
#include <math.h>

#define H 2048
#define V 50257
#define G3H (3 * H)   // 6144

// ---------------------------------------------------------------------------
// K1: GRU matvecs. One wave (64 lanes) per row j in [0, 3H).
// Computes gi[j] = w_ih[j,:]·word + b_ih[j]  and gh[j] = w_hh[j,:]·h0 + b_hh[j]
// ---------------------------------------------------------------------------
__global__ __launch_bounds__(256) void gru_matvec_kernel(
    const float* __restrict__ word, const float* __restrict__ h0,
    const float* __restrict__ w_ih, const float* __restrict__ w_hh,
    const float* __restrict__ b_ih, const float* __restrict__ b_hh,
    float* __restrict__ gi, float* __restrict__ gh) {
    const int wid_in_blk = threadIdx.x >> 6;
    const int lane = threadIdx.x & 63;
    const int row = blockIdx.x * 4 + wid_in_blk;
    if (row >= G3H) return;

    const float4* wi = reinterpret_cast<const float4*>(w_ih + (size_t)row * H);
    const float4* wh = reinterpret_cast<const float4*>(w_hh + (size_t)row * H);
    const float4* x4 = reinterpret_cast<const float4*>(word);
    const float4* h4 = reinterpret_cast<const float4*>(h0);

    float acc_i = 0.f, acc_h = 0.f;
    // H/4 = 512 float4 per row; 8 iterations per lane
    #pragma unroll
    for (int k = lane; k < H / 4; k += 64) {
        float4 a = wi[k];
        float4 x = x4[k];
        acc_i += a.x * x.x + a.y * x.y + a.z * x.z + a.w * x.w;
        float4 b = wh[k];
        float4 h = h4[k];
        acc_h += b.x * h.x + b.y * h.y + b.z * h.z + b.w * h.w;
    }
    #pragma unroll
    for (int off = 32; off > 0; off >>= 1) {
        acc_i += __shfl_down(acc_i, off, 64);
        acc_h += __shfl_down(acc_h, off, 64);
    }
    if (lane == 0) {
        gi[row] = acc_i + b_ih[row];
        gh[row] = acc_h + b_hh[row];
    }
}

// ---------------------------------------------------------------------------
// K2: gate math + h_new.  h_new -> out[V + j]
// ---------------------------------------------------------------------------
__global__ __launch_bounds__(256) void gru_gate_kernel(
    const float* __restrict__ gi, const float* __restrict__ gh,
    const float* __restrict__ h0, float* __restrict__ out_hnew) {
    int j = blockIdx.x * blockDim.x + threadIdx.x;
    if (j >= H) return;
    float r = 1.f / (1.f + expf(-(gi[j] + gh[j])));
    float z = 1.f / (1.f + expf(-(gi[H + j] + gh[H + j])));
    float n = tanhf(gi[2 * H + j] + r * gh[2 * H + j]);
    out_hnew[j] = (1.f - z) * n + z * h0[j];
}

// ---------------------------------------------------------------------------
// K3: logits matvec. One wave per vocab row v.
// logits[v] = lin_w[v,:]·h0 + lin_b[v]
// ---------------------------------------------------------------------------
__global__ __launch_bounds__(256) void logits_kernel(
    const float* __restrict__ lin_w, const float* __restrict__ lin_b,
    const float* __restrict__ h0, float* __restrict__ logits) {
    const int wid_in_blk = threadIdx.x >> 6;
    const int lane = threadIdx.x & 63;
    const int row = blockIdx.x * 4 + wid_in_blk;
    if (row >= V) return;

    const float4* w4 = reinterpret_cast<const float4*>(lin_w + (size_t)row * H);
    const float4* h4 = reinterpret_cast<const float4*>(h0);

    float acc = 0.f;
    #pragma unroll
    for (int k = lane; k < H / 4; k += 64) {
        float4 a = w4[k];
        float4 h = h4[k];
        acc += a.x * h.x + a.y * h.y + a.z * h.z + a.w * h.w;
    }
    #pragma unroll
    for (int off = 32; off > 0; off >>= 1) acc += __shfl_down(acc, off, 64);
    if (lane == 0) logits[row] = acc + lin_b[row];
}

// ---------------------------------------------------------------------------
// K4: single-block softmax reduction: global max, then sum of exp.
// Writes scalars[0] = max, scalars[1] = 1/sum.
// ---------------------------------------------------------------------------
__global__ __launch_bounds__(1024) void softmax_reduce_kernel(
    const float* __restrict__ logits, float* __restrict__ scalars) {
    __shared__ float red_m[16];
    __shared__ float red_s[16];
    const int tid = threadIdx.x;
    const int lane = tid & 63;
    const int wid = tid >> 6;           // 16 waves
    const int nthreads = 1024;

    float m = -INFINITY;
    for (int v = tid; v < V; v += nthreads) m = fmaxf(m, logits[v]);
    #pragma unroll
    for (int off = 32; off > 0; off >>= 1) m = fmaxf(m, __shfl_down(m, off, 64));
    if (lane == 0) red_m[wid] = m;
    __syncthreads();
    if (wid == 0) {
        float mm = (lane < 16) ? red_m[lane] : -INFINITY;
        #pragma unroll
        for (int off = 32; off > 0; off >>= 1) mm = fmaxf(mm, __shfl_down(mm, off, 64));
        if (lane == 0) red_m[0] = mm;
    }
    __syncthreads();
    const float gmax = red_m[0];

    float s = 0.f;
    for (int v = tid; v < V; v += nthreads) s += expf(logits[v] - gmax);
    #pragma unroll
    for (int off = 32; off > 0; off >>= 1) s += __shfl_down(s, off, 64);
    if (lane == 0) red_s[wid] = s;
    __syncthreads();
    if (wid == 0) {
        float ss = (lane < 16) ? red_s[lane] : 0.f;
        #pragma unroll
        for (int off = 32; off > 0; off >>= 1) ss += __shfl_down(ss, off, 64);
        if (lane == 0) {
            scalars[0] = gmax;
            scalars[1] = 1.f / ss;
        }
    }
}

// ---------------------------------------------------------------------------
// K5: probs[v] = exp(logits[v] - max) * invsum  -> out[0:V]
// ---------------------------------------------------------------------------
__global__ __launch_bounds__(256) void probs_kernel(
    const float* __restrict__ logits, const float* __restrict__ scalars,
    float* __restrict__ out_probs) {
    int v = blockIdx.x * blockDim.x + threadIdx.x;
    if (v >= V) return;
    out_probs[v] = expf(logits[v] - scalars[0]) * scalars[1];
}

extern "C" void kernel_launch(void* const* d_in, const int* in_sizes, int n_in,
                              void* d_out, int out_size, void* d_ws, size_t ws_size,
                              hipStream_t stream) {
    const float* word = (const float*)d_in[0];
    const float* hidden = (const float*)d_in[1];   // h0, 2048 f32
    const float* w_ih = (const float*)d_in[2];
    const float* w_hh = (const float*)d_in[3];
    const float* b_ih = (const float*)d_in[4];
    const float* b_hh = (const float*)d_in[5];
    const float* lin_w = (const float*)d_in[6];
    const float* lin_b = (const float*)d_in[7];

    float* out = (float*)d_out;           // [0:V] probs, [V:V+H] h_new
    float* ws = (float*)d_ws;
    float* gi = ws;                       // 3H
    float* gh = ws + G3H;                 // 3H
    float* logits = ws + 2 * G3H;         // V
    float* scalars = ws + 2 * G3H + V + 15; // 2 (padded offset, 16B align-ish)

    // K1: GRU matvecs (6144 rows, 4 waves/block)
    gru_matvec_kernel<<<G3H / 4, 256, 0, stream>>>(word, hidden, w_ih, w_hh,
                                                   b_ih, b_hh, gi, gh);
    // K3: logits matvec (independent of K1/K2 but same stream; dominant cost)
    logits_kernel<<<(V + 3) / 4, 256, 0, stream>>>(lin_w, lin_b, hidden, logits);
    // K2: gates -> h_new
    gru_gate_kernel<<<(H + 255) / 256, 256, 0, stream>>>(gi, gh, hidden, out + V);
    // K4: softmax reduction
    softmax_reduce_kernel<<<1, 1024, 0, stream>>>(logits, scalars);
    // K5: probs
    probs_kernel<<<(V + 255) / 256, 256, 0, stream>>>(logits, scalars, out);
}

// Round 2
// 103.894 us; speedup vs baseline: 1.0575x; 1.0575x over previous
//
#include <hip/hip_runtime.h>
#include <hip/hip_bf16.h>
#include <math.h>

#define H 2048
#define V 50257
#define KV4 (H / 4)      // 512 float4 per row
#define NBSM 128         // softmax partial blocks

typedef float f4 __attribute__((ext_vector_type(4)));

__device__ __forceinline__ f4 ntload(const f4* p) {
    return __builtin_nontemporal_load(p);
}

__device__ __forceinline__ float wave_reduce_sum(float x) {
    #pragma unroll
    for (int off = 32; off; off >>= 1) x += __shfl_down(x, off, 64);
    return x;
}

__device__ __forceinline__ float wave_allreduce_max(float x) {
    #pragma unroll
    for (int off = 32; off; off >>= 1) x = fmaxf(x, __shfl_xor(x, off, 64));
    return x;
}

// ---------------------------------------------------------------------------
// K1: fully fused GRU cell. Block = 384 threads = 6 waves; block handles 4
// hidden indices j0..j0+3. Wave w in [0,6): matrix = (w<3 ? w_ih : w_hh),
// gate = w%3, vector = (w<3 ? word : h0). Each wave computes 4 dot products
// (rows gate*H + j0+jj) sharing one vector load stream. Gate math in-block.
// ---------------------------------------------------------------------------
__global__ __launch_bounds__(384) void gru_fused_kernel(
    const float* __restrict__ word, const float* __restrict__ h0,
    const float* __restrict__ w_ih, const float* __restrict__ w_hh,
    const float* __restrict__ b_ih, const float* __restrict__ b_hh,
    float* __restrict__ out_hnew) {
    __shared__ float red[6][4];
    const int lane = threadIdx.x & 63;
    const int w = threadIdx.x >> 6;            // 0..5
    const int j0 = blockIdx.x * 4;
    const int gate = (w < 3) ? w : (w - 3);    // 0=r,1=z,2=n
    const float* W = (w < 3) ? w_ih : w_hh;
    const f4* vec = reinterpret_cast<const f4*>((w < 3) ? word : h0);

    const size_t rb = (size_t)(gate * H + j0) * H;
    const f4* r0 = reinterpret_cast<const f4*>(W + rb);
    const f4* r1 = reinterpret_cast<const f4*>(W + rb + H);
    const f4* r2 = reinterpret_cast<const f4*>(W + rb + 2 * H);
    const f4* r3 = reinterpret_cast<const f4*>(W + rb + 3 * H);

    float a0 = 0.f, a1 = 0.f, a2 = 0.f, a3 = 0.f;
    #pragma unroll 4
    for (int k = lane; k < KV4; k += 64) {
        f4 x = vec[k];
        f4 p0 = ntload(&r0[k]);
        a0 += p0.x * x.x + p0.y * x.y + p0.z * x.z + p0.w * x.w;
        f4 p1 = ntload(&r1[k]);
        a1 += p1.x * x.x + p1.y * x.y + p1.z * x.z + p1.w * x.w;
        f4 p2 = ntload(&r2[k]);
        a2 += p2.x * x.x + p2.y * x.y + p2.z * x.z + p2.w * x.w;
        f4 p3 = ntload(&r3[k]);
        a3 += p3.x * x.x + p3.y * x.y + p3.z * x.z + p3.w * x.w;
    }
    a0 = wave_reduce_sum(a0);
    a1 = wave_reduce_sum(a1);
    a2 = wave_reduce_sum(a2);
    a3 = wave_reduce_sum(a3);
    if (lane == 0) {
        red[w][0] = a0; red[w][1] = a1; red[w][2] = a2; red[w][3] = a3;
    }
    __syncthreads();
    if (threadIdx.x < 4) {
        const int jj = threadIdx.x;
        const int j = j0 + jj;
        float ir = red[0][jj] + b_ih[j];
        float iz = red[1][jj] + b_ih[H + j];
        float in_ = red[2][jj] + b_ih[2 * H + j];
        float hr = red[3][jj] + b_hh[j];
        float hz = red[4][jj] + b_hh[H + j];
        float hn = red[5][jj] + b_hh[2 * H + j];
        float r = 1.f / (1.f + expf(-(ir + hr)));
        float z = 1.f / (1.f + expf(-(iz + hz)));
        float n = tanhf(in_ + r * hn);
        out_hnew[j] = (1.f - z) * n + z * h0[j];
    }
}

// ---------------------------------------------------------------------------
// K3: logits matvec. 4 waves/block, 4 rows/wave => 16 rows/block.
// logits[v] = lin_w[v,:]·h0 + lin_b[v]
// ---------------------------------------------------------------------------
__global__ __launch_bounds__(256) void logits_kernel(
    const float* __restrict__ lin_w, const float* __restrict__ lin_b,
    const float* __restrict__ h0, float* __restrict__ logits) {
    const int lane = threadIdx.x & 63;
    const int wid = threadIdx.x >> 6;
    const int row0 = (blockIdx.x * 4 + wid) * 4;
    // clamp so loads stay in-bounds; writes are guarded
    const int q0 = min(row0 + 0, V - 1);
    const int q1 = min(row0 + 1, V - 1);
    const int q2 = min(row0 + 2, V - 1);
    const int q3 = min(row0 + 3, V - 1);
    const f4* w0 = reinterpret_cast<const f4*>(lin_w + (size_t)q0 * H);
    const f4* w1 = reinterpret_cast<const f4*>(lin_w + (size_t)q1 * H);
    const f4* w2 = reinterpret_cast<const f4*>(lin_w + (size_t)q2 * H);
    const f4* w3 = reinterpret_cast<const f4*>(lin_w + (size_t)q3 * H);
    const f4* h4 = reinterpret_cast<const f4*>(h0);

    float a0 = 0.f, a1 = 0.f, a2 = 0.f, a3 = 0.f;
    #pragma unroll 4
    for (int k = lane; k < KV4; k += 64) {
        f4 h = h4[k];
        f4 p0 = ntload(&w0[k]);
        a0 += p0.x * h.x + p0.y * h.y + p0.z * h.z + p0.w * h.w;
        f4 p1 = ntload(&w1[k]);
        a1 += p1.x * h.x + p1.y * h.y + p1.z * h.z + p1.w * h.w;
        f4 p2 = ntload(&w2[k]);
        a2 += p2.x * h.x + p2.y * h.y + p2.z * h.z + p2.w * h.w;
        f4 p3 = ntload(&w3[k]);
        a3 += p3.x * h.x + p3.y * h.y + p3.z * h.z + p3.w * h.w;
    }
    a0 = wave_reduce_sum(a0);
    a1 = wave_reduce_sum(a1);
    a2 = wave_reduce_sum(a2);
    a3 = wave_reduce_sum(a3);
    if (lane == 0) {
        if (row0 + 0 < V) logits[row0 + 0] = a0 + lin_b[row0 + 0];
        if (row0 + 1 < V) logits[row0 + 1] = a1 + lin_b[row0 + 1];
        if (row0 + 2 < V) logits[row0 + 2] = a2 + lin_b[row0 + 2];
        if (row0 + 3 < V) logits[row0 + 3] = a3 + lin_b[row0 + 3];
    }
}

// ---------------------------------------------------------------------------
// K4a: per-block softmax partials over a contiguous chunk: (max, sumexp)
// ---------------------------------------------------------------------------
__global__ __launch_bounds__(256) void softmax_partial_kernel(
    const float* __restrict__ logits, float* __restrict__ pm,
    float* __restrict__ ps) {
    __shared__ float rm[4], rs[4];
    const int tid = threadIdx.x;
    const int lane = tid & 63;
    const int wid = tid >> 6;
    const int chunk = (V + NBSM - 1) / NBSM;   // 393
    const int start = blockIdx.x * chunk;
    const int end = min(V, start + chunk);

    float m = -INFINITY;
    for (int v = start + tid; v < end; v += 256) m = fmaxf(m, logits[v]);
    m = wave_allreduce_max(m);
    if (lane == 0) rm[wid] = m;
    __syncthreads();
    m = fmaxf(fmaxf(rm[0], rm[1]), fmaxf(rm[2], rm[3]));

    float s = 0.f;
    for (int v = start + tid; v < end; v += 256) s += expf(logits[v] - m);
    s = wave_reduce_sum(s);
    if (lane == 0) rs[wid] = s;
    __syncthreads();
    if (tid == 0) {
        pm[blockIdx.x] = m;
        ps[blockIdx.x] = rs[0] + rs[1] + rs[2] + rs[3];
    }
}

// ---------------------------------------------------------------------------
// K5: combine partials (redundantly per block, cheap: 128 pairs from L2)
// then probs[v] = exp(logits[v] - M) / S
// ---------------------------------------------------------------------------
__global__ __launch_bounds__(256) void probs_kernel(
    const float* __restrict__ logits, const float* __restrict__ pm,
    const float* __restrict__ ps, float* __restrict__ out_probs) {
    __shared__ float sM, sInvS;
    if (threadIdx.x < 64) {
        const int lane = threadIdx.x;
        float m0 = pm[lane], s0 = ps[lane];
        float m1 = pm[lane + 64], s1 = ps[lane + 64];
        float M = fmaxf(m0, m1);
        float S = s0 * expf(m0 - M) + s1 * expf(m1 - M);
        #pragma unroll
        for (int off = 32; off; off >>= 1) {
            float Mo = __shfl_xor(M, off, 64);
            float So = __shfl_xor(S, off, 64);
            float Mn = fmaxf(M, Mo);
            S = S * expf(M - Mn) + So * expf(Mo - Mn);
            M = Mn;
        }
        if (lane == 0) { sM = M; sInvS = 1.f / S; }
    }
    __syncthreads();
    const int v = blockIdx.x * 256 + threadIdx.x;
    if (v < V) out_probs[v] = expf(logits[v] - sM) * sInvS;
}

extern "C" void kernel_launch(void* const* d_in, const int* in_sizes, int n_in,
                              void* d_out, int out_size, void* d_ws, size_t ws_size,
                              hipStream_t stream) {
    const float* word = (const float*)d_in[0];
    const float* hidden = (const float*)d_in[1];   // h0, 2048 f32
    const float* w_ih = (const float*)d_in[2];
    const float* w_hh = (const float*)d_in[3];
    const float* b_ih = (const float*)d_in[4];
    const float* b_hh = (const float*)d_in[5];
    const float* lin_w = (const float*)d_in[6];
    const float* lin_b = (const float*)d_in[7];

    float* out = (float*)d_out;            // [0:V] probs, [V:V+H] h_new
    float* ws = (float*)d_ws;
    float* logits = ws;                    // V
    float* pm = ws + V + 64;               // NBSM
    float* ps = pm + NBSM;                 // NBSM

    // K3: logits matvec (dominant, 412 MB)
    logits_kernel<<<(V + 15) / 16, 256, 0, stream>>>(lin_w, lin_b, hidden, logits);
    // K1: fused GRU cell (100 MB)
    gru_fused_kernel<<<H / 4, 384, 0, stream>>>(word, hidden, w_ih, w_hh,
                                                b_ih, b_hh, out + V);
    // K4a: softmax partials
    softmax_partial_kernel<<<NBSM, 256, 0, stream>>>(logits, pm, ps);
    // K5: combine + normalize
    probs_kernel<<<(V + 255) / 256, 256, 0, stream>>>(logits, pm, ps, out);
}

// Round 3
// 98.589 us; speedup vs baseline: 1.1144x; 1.0538x over previous
//
#include <hip/hip_runtime.h>
#include <hip/hip_bf16.h>
#include <math.h>

#define H 2048
#define V 50257
#define KV4 (H / 4)          // 512 float4 per row
#define NB_LOG 3142          // ceil(V/16) logits blocks, 16 rows each
#define NB_GRU 768           // 12288 GRU rows / 16
#define NPART NB_LOG

typedef float f4 __attribute__((ext_vector_type(4)));

__device__ __forceinline__ f4 ntload(const f4* p) {
    return __builtin_nontemporal_load(p);
}

__device__ __forceinline__ float wave_reduce_sum(float x) {
    #pragma unroll
    for (int off = 32; off; off >>= 1) x += __shfl_down(x, off, 64);
    return x;
}

// ---------------------------------------------------------------------------
// K_A: mega matvec, one launch for ALL heavy HBM traffic (512 MB).
// Blocks [0, NB_LOG): logits rows (lin_w @ h0 + lin_b), 4 waves x 4 rows,
//   plus block-local softmax partial (max, sumexp) written to pm/ps.
// Blocks [NB_LOG, NB_LOG+NB_GRU): GRU rows. First 384 blocks: w_ih @ word
//   + b_ih -> gi.  Next 384: w_hh @ h0 + b_hh -> gh. Regions block-aligned.
// ---------------------------------------------------------------------------
__global__ __launch_bounds__(256) void mega_matvec_kernel(
    const float* __restrict__ word, const float* __restrict__ h0,
    const float* __restrict__ w_ih, const float* __restrict__ w_hh,
    const float* __restrict__ b_ih, const float* __restrict__ b_hh,
    const float* __restrict__ lin_w, const float* __restrict__ lin_b,
    float* __restrict__ gi, float* __restrict__ gh,
    float* __restrict__ logits, float* __restrict__ pm,
    float* __restrict__ ps) {
    const int lane = threadIdx.x & 63;
    const int wid = threadIdx.x >> 6;
    __shared__ float lbuf[16];

    const float* Wm;
    const f4* vec;
    const float* bias;
    float* dst;
    int r0, maxrow;
    const bool is_log = ((int)blockIdx.x < NB_LOG);
    if (is_log) {
        Wm = lin_w; vec = reinterpret_cast<const f4*>(h0);
        bias = lin_b; dst = logits;
        r0 = blockIdx.x * 16 + wid * 4;
        maxrow = V;
    } else {
        const int g = blockIdx.x - NB_LOG;         // 0..767
        if (g < 384) {
            Wm = w_ih; vec = reinterpret_cast<const f4*>(word);
            bias = b_ih; dst = gi;
            r0 = g * 16 + wid * 4;
        } else {
            Wm = w_hh; vec = reinterpret_cast<const f4*>(h0);
            bias = b_hh; dst = gh;
            r0 = (g - 384) * 16 + wid * 4;
        }
        maxrow = 3 * H;
    }

    const int q0 = min(r0 + 0, maxrow - 1);
    const int q1 = min(r0 + 1, maxrow - 1);
    const int q2 = min(r0 + 2, maxrow - 1);
    const int q3 = min(r0 + 3, maxrow - 1);
    const f4* w0 = reinterpret_cast<const f4*>(Wm + (size_t)q0 * H);
    const f4* w1 = reinterpret_cast<const f4*>(Wm + (size_t)q1 * H);
    const f4* w2 = reinterpret_cast<const f4*>(Wm + (size_t)q2 * H);
    const f4* w3 = reinterpret_cast<const f4*>(Wm + (size_t)q3 * H);

    float a0 = 0.f, a1 = 0.f, a2 = 0.f, a3 = 0.f;
    #pragma unroll 4
    for (int k = lane; k < KV4; k += 64) {
        f4 x = vec[k];
        f4 p0 = ntload(&w0[k]);
        a0 += p0.x * x.x + p0.y * x.y + p0.z * x.z + p0.w * x.w;
        f4 p1 = ntload(&w1[k]);
        a1 += p1.x * x.x + p1.y * x.y + p1.z * x.z + p1.w * x.w;
        f4 p2 = ntload(&w2[k]);
        a2 += p2.x * x.x + p2.y * x.y + p2.z * x.z + p2.w * x.w;
        f4 p3 = ntload(&w3[k]);
        a3 += p3.x * x.x + p3.y * x.y + p3.z * x.z + p3.w * x.w;
    }
    a0 = wave_reduce_sum(a0);
    a1 = wave_reduce_sum(a1);
    a2 = wave_reduce_sum(a2);
    a3 = wave_reduce_sum(a3);

    if (lane == 0) {
        const float v0 = a0 + bias[q0];
        const float v1 = a1 + bias[q1];
        const float v2 = a2 + bias[q2];
        const float v3 = a3 + bias[q3];
        if (r0 + 0 < maxrow) dst[r0 + 0] = v0;
        if (r0 + 1 < maxrow) dst[r0 + 1] = v1;
        if (r0 + 2 < maxrow) dst[r0 + 2] = v2;
        if (r0 + 3 < maxrow) dst[r0 + 3] = v3;
        if (is_log) {
            lbuf[wid * 4 + 0] = (r0 + 0 < maxrow) ? v0 : -INFINITY;
            lbuf[wid * 4 + 1] = (r0 + 1 < maxrow) ? v1 : -INFINITY;
            lbuf[wid * 4 + 2] = (r0 + 2 < maxrow) ? v2 : -INFINITY;
            lbuf[wid * 4 + 3] = (r0 + 3 < maxrow) ? v3 : -INFINITY;
        }
    }
    if (is_log) {
        __syncthreads();
        if (threadIdx.x < 16) {
            const float x = lbuf[threadIdx.x];
            float m = x;
            #pragma unroll
            for (int off = 8; off; off >>= 1)
                m = fmaxf(m, __shfl_xor(m, off, 16));
            float s = expf(x - m);          // exp(-inf - m) == 0 for pad rows
            #pragma unroll
            for (int off = 8; off; off >>= 1)
                s += __shfl_xor(s, off, 16);
            if (threadIdx.x == 0) {
                pm[blockIdx.x] = m;
                ps[blockIdx.x] = s;
            }
        }
    }
}

// ---------------------------------------------------------------------------
// K_B: finish. Blocks [0,50): combine NPART partials (L2-resident, redundant
// per block) then probs over 1024 logits each. Block 50: GRU gate math.
// ---------------------------------------------------------------------------
__global__ __launch_bounds__(256) void finish_kernel(
    const float* __restrict__ logits, const float* __restrict__ pm,
    const float* __restrict__ ps, const float* __restrict__ gi,
    const float* __restrict__ gh, const float* __restrict__ h0,
    float* __restrict__ out) {
    if ((int)blockIdx.x < 50) {
        __shared__ float redM[4], redS[4];
        __shared__ float sM, sInvS;
        const int lane = threadIdx.x & 63;
        const int wid = threadIdx.x >> 6;

        float M = -INFINITY, S = 0.f;
        for (int p = threadIdx.x; p < NPART; p += 256) {
            const float m = pm[p], s = ps[p];
            const float Mn = fmaxf(M, m);
            S = S * expf(M - Mn) + s * expf(m - Mn);
            M = Mn;
        }
        #pragma unroll
        for (int off = 32; off; off >>= 1) {
            const float Mo = __shfl_xor(M, off, 64);
            const float So = __shfl_xor(S, off, 64);
            const float Mn = fmaxf(M, Mo);
            S = S * expf(M - Mn) + So * expf(Mo - Mn);
            M = Mn;
        }
        if (lane == 0) { redM[wid] = M; redS[wid] = S; }
        __syncthreads();
        if (threadIdx.x == 0) {
            float M4 = redM[0], S4 = redS[0];
            #pragma unroll
            for (int w = 1; w < 4; ++w) {
                const float Mn = fmaxf(M4, redM[w]);
                S4 = S4 * expf(M4 - Mn) + redS[w] * expf(redM[w] - Mn);
                M4 = Mn;
            }
            sM = M4;
            sInvS = 1.f / S4;
        }
        __syncthreads();
        const float gm = sM, gis = sInvS;
        const int base = blockIdx.x * 1024 + threadIdx.x;
        #pragma unroll
        for (int i = 0; i < 4; ++i) {
            const int v = base + i * 256;
            if (v < V) out[v] = expf(logits[v] - gm) * gis;
        }
    } else {
        // gate math: 2048 elements, 256 threads x 8
        #pragma unroll
        for (int i = 0; i < 8; ++i) {
            const int j = threadIdx.x + i * 256;
            const float r = 1.f / (1.f + expf(-(gi[j] + gh[j])));
            const float z = 1.f / (1.f + expf(-(gi[H + j] + gh[H + j])));
            const float n = tanhf(gi[2 * H + j] + r * gh[2 * H + j]);
            out[V + j] = (1.f - z) * n + z * h0[j];
        }
    }
}

extern "C" void kernel_launch(void* const* d_in, const int* in_sizes, int n_in,
                              void* d_out, int out_size, void* d_ws, size_t ws_size,
                              hipStream_t stream) {
    const float* word = (const float*)d_in[0];
    const float* hidden = (const float*)d_in[1];   // h0, 2048 f32
    const float* w_ih = (const float*)d_in[2];
    const float* w_hh = (const float*)d_in[3];
    const float* b_ih = (const float*)d_in[4];
    const float* b_hh = (const float*)d_in[5];
    const float* lin_w = (const float*)d_in[6];
    const float* lin_b = (const float*)d_in[7];

    float* out = (float*)d_out;            // [0:V] probs, [V:V+H] h_new
    float* ws = (float*)d_ws;
    float* logits = ws;                    // V (pad to 50304)
    float* pm = ws + 50304;                // NPART
    float* ps = ws + 50304 + 3200;         // NPART
    float* gi = ws + 50304 + 6400;         // 3H
    float* gh = ws + 50304 + 6400 + 3 * H; // 3H

    mega_matvec_kernel<<<NB_LOG + NB_GRU, 256, 0, stream>>>(
        word, hidden, w_ih, w_hh, b_ih, b_hh, lin_w, lin_b,
        gi, gh, logits, pm, ps);
    finish_kernel<<<51, 256, 0, stream>>>(logits, pm, ps, gi, gh, hidden, out);
}

// Round 4
// 91.052 us; speedup vs baseline: 1.2066x; 1.0828x over previous
//
#include <hip/hip_runtime.h>
#include <hip/hip_bf16.h>
#include <math.h>

#define H 2048
#define V 50257
#define KV4 (H / 4)          // 512 float4 per row
#define NB_LOG 3142          // ceil(V/16) logits blocks, 16 rows each
#define NB_GRU 768           // 12288 GRU rows / 16
#define NPART NB_LOG

typedef float f4 __attribute__((ext_vector_type(4)));

__device__ __forceinline__ f4 ntload(const f4* p) {
    return __builtin_nontemporal_load(p);
}

__device__ __forceinline__ float wave_reduce_sum(float x) {
    #pragma unroll
    for (int off = 32; off; off >>= 1) x += __shfl_down(x, off, 64);
    return x;
}

// ---------------------------------------------------------------------------
// K_A: mega matvec, one launch for ALL heavy HBM traffic (512 MB).
// The multiplying vector is PRELOADED into 8 f4 registers per lane (lane l
// only ever needs vec[l + i*64]), so the hot loop is pure weight streaming:
// 4 global loads + 4 dot4 per iteration, 16 loads in flight.
// Blocks [0, NB_LOG): logits rows + block-local softmax partial (m, sumexp).
// Blocks [NB_LOG, ..): GRU rows -> gi / gh.
// ---------------------------------------------------------------------------
__global__ __launch_bounds__(256, 4) void mega_matvec_kernel(
    const float* __restrict__ word, const float* __restrict__ h0,
    const float* __restrict__ w_ih, const float* __restrict__ w_hh,
    const float* __restrict__ b_ih, const float* __restrict__ b_hh,
    const float* __restrict__ lin_w, const float* __restrict__ lin_b,
    float* __restrict__ gi, float* __restrict__ gh,
    float* __restrict__ logits, float* __restrict__ pm,
    float* __restrict__ ps) {
    const int lane = threadIdx.x & 63;
    const int wid = threadIdx.x >> 6;
    __shared__ float lbuf[16];

    const float* Wm;
    const f4* vec;
    const float* bias;
    float* dst;
    int r0, maxrow;
    const bool is_log = ((int)blockIdx.x < NB_LOG);
    if (is_log) {
        Wm = lin_w; vec = reinterpret_cast<const f4*>(h0);
        bias = lin_b; dst = logits;
        r0 = blockIdx.x * 16 + wid * 4;
        maxrow = V;
    } else {
        const int g = blockIdx.x - NB_LOG;         // 0..767
        if (g < 384) {
            Wm = w_ih; vec = reinterpret_cast<const f4*>(word);
            bias = b_ih; dst = gi;
            r0 = g * 16 + wid * 4;
        } else {
            Wm = w_hh; vec = reinterpret_cast<const f4*>(h0);
            bias = b_hh; dst = gh;
            r0 = (g - 384) * 16 + wid * 4;
        }
        maxrow = 3 * H;
    }

    // preload the multiplying vector: lane l uses exactly vec[l + i*64]
    f4 x[8];
    #pragma unroll
    for (int i = 0; i < 8; ++i) x[i] = vec[lane + i * 64];

    const int q0 = min(r0 + 0, maxrow - 1);
    const int q1 = min(r0 + 1, maxrow - 1);
    const int q2 = min(r0 + 2, maxrow - 1);
    const int q3 = min(r0 + 3, maxrow - 1);
    const f4* w0 = reinterpret_cast<const f4*>(Wm + (size_t)q0 * H);
    const f4* w1 = reinterpret_cast<const f4*>(Wm + (size_t)q1 * H);
    const f4* w2 = reinterpret_cast<const f4*>(Wm + (size_t)q2 * H);
    const f4* w3 = reinterpret_cast<const f4*>(Wm + (size_t)q3 * H);

    float a0 = 0.f, a1 = 0.f, a2 = 0.f, a3 = 0.f;
    #pragma unroll 4
    for (int i = 0; i < 8; ++i) {
        const int k = lane + i * 64;
        f4 p0 = ntload(&w0[k]);
        a0 += p0.x * x[i].x + p0.y * x[i].y + p0.z * x[i].z + p0.w * x[i].w;
        f4 p1 = ntload(&w1[k]);
        a1 += p1.x * x[i].x + p1.y * x[i].y + p1.z * x[i].z + p1.w * x[i].w;
        f4 p2 = ntload(&w2[k]);
        a2 += p2.x * x[i].x + p2.y * x[i].y + p2.z * x[i].z + p2.w * x[i].w;
        f4 p3 = ntload(&w3[k]);
        a3 += p3.x * x[i].x + p3.y * x[i].y + p3.z * x[i].z + p3.w * x[i].w;
    }
    a0 = wave_reduce_sum(a0);
    a1 = wave_reduce_sum(a1);
    a2 = wave_reduce_sum(a2);
    a3 = wave_reduce_sum(a3);

    if (lane == 0) {
        const float v0 = a0 + bias[q0];
        const float v1 = a1 + bias[q1];
        const float v2 = a2 + bias[q2];
        const float v3 = a3 + bias[q3];
        if (r0 + 0 < maxrow) dst[r0 + 0] = v0;
        if (r0 + 1 < maxrow) dst[r0 + 1] = v1;
        if (r0 + 2 < maxrow) dst[r0 + 2] = v2;
        if (r0 + 3 < maxrow) dst[r0 + 3] = v3;
        if (is_log) {
            lbuf[wid * 4 + 0] = (r0 + 0 < maxrow) ? v0 : -INFINITY;
            lbuf[wid * 4 + 1] = (r0 + 1 < maxrow) ? v1 : -INFINITY;
            lbuf[wid * 4 + 2] = (r0 + 2 < maxrow) ? v2 : -INFINITY;
            lbuf[wid * 4 + 3] = (r0 + 3 < maxrow) ? v3 : -INFINITY;
        }
    }
    if (is_log) {
        __syncthreads();
        if (threadIdx.x < 16) {
            const float xv = lbuf[threadIdx.x];
            float m = xv;
            #pragma unroll
            for (int off = 8; off; off >>= 1)
                m = fmaxf(m, __shfl_xor(m, off, 16));
            float s = expf(xv - m);         // exp(-inf - m) == 0 for pad rows
            #pragma unroll
            for (int off = 8; off; off >>= 1)
                s += __shfl_xor(s, off, 16);
            if (threadIdx.x == 0) {
                pm[blockIdx.x] = m;
                ps[blockIdx.x] = s;
            }
        }
    }
}

// ---------------------------------------------------------------------------
// K_B: finish. Blocks [0,50): combine NPART partials (L2/L3-resident,
// redundant per block) then probs over 1024 logits each. Block 50: gates.
// ---------------------------------------------------------------------------
__global__ __launch_bounds__(256) void finish_kernel(
    const float* __restrict__ logits, const float* __restrict__ pm,
    const float* __restrict__ ps, const float* __restrict__ gi,
    const float* __restrict__ gh, const float* __restrict__ h0,
    float* __restrict__ out) {
    if ((int)blockIdx.x < 50) {
        __shared__ float redM[4], redS[4];
        __shared__ float sM, sInvS;
        const int lane = threadIdx.x & 63;
        const int wid = threadIdx.x >> 6;

        float M = -INFINITY, S = 0.f;
        for (int p = threadIdx.x; p < NPART; p += 256) {
            const float m = pm[p], s = ps[p];
            const float Mn = fmaxf(M, m);
            S = S * expf(M - Mn) + s * expf(m - Mn);
            M = Mn;
        }
        #pragma unroll
        for (int off = 32; off; off >>= 1) {
            const float Mo = __shfl_xor(M, off, 64);
            const float So = __shfl_xor(S, off, 64);
            const float Mn = fmaxf(M, Mo);
            S = S * expf(M - Mn) + So * expf(Mo - Mn);
            M = Mn;
        }
        if (lane == 0) { redM[wid] = M; redS[wid] = S; }
        __syncthreads();
        if (threadIdx.x == 0) {
            float M4 = redM[0], S4 = redS[0];
            #pragma unroll
            for (int w = 1; w < 4; ++w) {
                const float Mn = fmaxf(M4, redM[w]);
                S4 = S4 * expf(M4 - Mn) + redS[w] * expf(redM[w] - Mn);
                M4 = Mn;
            }
            sM = M4;
            sInvS = 1.f / S4;
        }
        __syncthreads();
        const float gm = sM, gis = sInvS;
        const int base = blockIdx.x * 1024 + threadIdx.x;
        #pragma unroll
        for (int i = 0; i < 4; ++i) {
            const int v = base + i * 256;
            if (v < V) out[v] = expf(logits[v] - gm) * gis;
        }
    } else {
        // gate math: 2048 elements, 256 threads x 8
        #pragma unroll
        for (int i = 0; i < 8; ++i) {
            const int j = threadIdx.x + i * 256;
            const float r = 1.f / (1.f + expf(-(gi[j] + gh[j])));
            const float z = 1.f / (1.f + expf(-(gi[H + j] + gh[H + j])));
            const float n = tanhf(gi[2 * H + j] + r * gh[2 * H + j]);
            out[V + j] = (1.f - z) * n + z * h0[j];
        }
    }
}

extern "C" void kernel_launch(void* const* d_in, const int* in_sizes, int n_in,
                              void* d_out, int out_size, void* d_ws, size_t ws_size,
                              hipStream_t stream) {
    const float* word = (const float*)d_in[0];
    const float* hidden = (const float*)d_in[1];   // h0, 2048 f32
    const float* w_ih = (const float*)d_in[2];
    const float* w_hh = (const float*)d_in[3];
    const float* b_ih = (const float*)d_in[4];
    const float* b_hh = (const float*)d_in[5];
    const float* lin_w = (const float*)d_in[6];
    const float* lin_b = (const float*)d_in[7];

    float* out = (float*)d_out;            // [0:V] probs, [V:V+H] h_new
    float* ws = (float*)d_ws;
    float* logits = ws;                    // V (pad to 50304)
    float* pm = ws + 50304;                // NPART
    float* ps = ws + 50304 + 3200;         // NPART
    float* gi = ws + 50304 + 6400;         // 3H
    float* gh = ws + 50304 + 6400 + 3 * H; // 3H

    mega_matvec_kernel<<<NB_LOG + NB_GRU, 256, 0, stream>>>(
        word, hidden, w_ih, w_hh, b_ih, b_hh, lin_w, lin_b,
        gi, gh, logits, pm, ps);
    finish_kernel<<<51, 256, 0, stream>>>(logits, pm, ps, gi, gh, hidden, out);
}